// Round 8
// baseline (243.082 us; speedup 1.0000x reference)
//
#include <hip/hip_runtime.h>
#include <math.h>

#define BATCH  32768
#define D      128
#define K      6400
#define KC     64
#define ROWS_PER_BLOCK 64
#define GROUP_C 64
#define QUARTERS 4
#define GROUPS_PER_QUARTER 25     // 25 * 64 * 4 = 6400

typedef _Float16 half8 __attribute__((ext_vector_type(8)));
typedef float    floatx4 __attribute__((ext_vector_type(4)));

typedef __attribute__((address_space(3))) unsigned       lds_uint;
typedef __attribute__((address_space(1))) const unsigned glb_uint;

__device__ __forceinline__ void async_lds16(const void* g, void* l) {
    __builtin_amdgcn_global_load_lds((glb_uint*)g, (lds_uint*)l, 16, 0, 0);
}

// ---- pack centers to fp16 (group-major, 64-center groups) + c2h = +0.5*||c||^2 ----
// 16B unit n = g*1024 + u*64 + cw holds center (g*64+cw), k in [u*8, u*8+8).
__global__ __launch_bounds__(256) void pack_kernel(const float* __restrict__ centers,
                                                   _Float16* __restrict__ wh,
                                                   float* __restrict__ c2h) {
    int tid = blockIdx.x * 256 + threadIdx.x;   // 0 .. K*16-1
    int g  = tid >> 10;
    int u  = (tid >> 6) & 15;
    int cw = tid & 63;
    int center = g * GROUP_C + cw;
    const float* src = centers + (size_t)center * D + u * 8;
    float4 a = *(const float4*)src;
    float4 b = *(const float4*)(src + 4);
    float f[8] = {a.x, a.y, a.z, a.w, b.x, b.y, b.z, b.w};
    half8 h;
#pragma unroll
    for (int j = 0; j < 8; ++j) h[j] = (_Float16)f[j];
    *(half8*)(wh + (size_t)tid * 8) = h;

    // fused c2h: blocks 0..99 each cover 64 centers, 4 threads per center
    if (blockIdx.x < K / KC) {
        int c_local = threadIdx.x >> 2, part = threadIdx.x & 3;
        int c = blockIdx.x * 64 + c_local;
        const float4* p = (const float4*)(centers + (size_t)c * D + part * 32);
        float s = 0.f;
#pragma unroll
        for (int i = 0; i < 8; ++i) {
            float4 v = p[i];
            s = fmaf(v.x, v.x, s); s = fmaf(v.y, v.y, s);
            s = fmaf(v.z, v.z, s); s = fmaf(v.w, v.w, s);
        }
        s += __shfl_xor(s, 1, 64);
        s += __shfl_xor(s, 2, 64);
        if (part == 0) c2h[c] = 0.5f * s;
    }
}

// ---- distance + candidate kernel: key-packed argmin, 4-way center split ----
// Block: 256 thr = 4 waves = 2 rowquarters x 2 centerhalves; 64 rows/block;
// quarter q = blockIdx.y covers centers q*1600..+1599 in 25 groups of 64.
// A = fp16(-x) register-resident; acc init = c^2/2 + x^2/2 so acc_final =
// ||x-c||^2/2 >= 0 -> fp32 bits sortable as uint. Key = (bits & ~63) | (ci*2+ct):
// best-2 tracking is 3 uint min/max ops, no index regs in the hot loop.
// 32 KB LDS dbuf -> 5 blocks/CU; each SIMD hosts waves of 5 independent blocks
// (decorrelated barrier domains). Exact fp32 refine of 8 cand/row -> ws.
__global__ __launch_bounds__(256, 5) void dist_kernel(
    const float* __restrict__ x, const float* __restrict__ centers,
    const _Float16* __restrict__ wh, const float* __restrict__ c2h,
    float* __restrict__ ws_sq, int* __restrict__ ws_ix) {
    __shared__ char lds[32768];   // two 16 KB group buffers; aliased in epilogue

    const int t    = threadIdx.x;
    const int w    = t >> 6;
    const int L    = t & 63;
    const int quad = L >> 4;
    const int n16  = L & 15;
    const int rq      = w >> 1;   // row quarter (0,1) -> rows rq*32..
    const int chalf   = w & 1;    // center half of the 64-group
    const int q    = blockIdx.y;
    const int gr0  = blockIdx.x * ROWS_PER_BLOCK;

    // ---- preload A = fp16(-x) fragments + row norms x2/2 ----
    half8 Ah[2][4];
    float x2f[2];
#pragma unroll
    for (int rt = 0; rt < 2; ++rt) {
        int r = gr0 + rq * 32 + rt * 16 + n16;
        const float* xr = x + (size_t)r * D + quad * 8;
        float s = 0.f;
#pragma unroll
        for (int ks = 0; ks < 4; ++ks) {
            float4 a = *(const float4*)(xr + ks * 32);
            float4 b = *(const float4*)(xr + ks * 32 + 4);
            float f[8] = {a.x, a.y, a.z, a.w, b.x, b.y, b.z, b.w};
            half8 h;
#pragma unroll
            for (int j = 0; j < 8; ++j) {
                s = fmaf(f[j], f[j], s);
                h[j] = (_Float16)(-f[j]);
            }
            Ah[rt][ks] = h;
        }
        // reduce partial (this lane holds 32 of 128 dims) over the 4 quads
        s += __shfl_xor(s, 16, 64);
        s += __shfl_xor(s, 32, 64);
        x2f[rt] = s;
    }
    // x2q[rt][reg] = 0.5*||x_row||^2 for acc row = quad*4+reg (C/D layout)
    float x2q[2][4];
#pragma unroll
    for (int rt = 0; rt < 2; ++rt)
#pragma unroll
        for (int reg = 0; reg < 4; ++reg)
            x2q[rt][reg] = 0.5f * __shfl(x2f[rt], quad * 4 + reg, 64);

    // best-2 keys (uint min) per slot k = rt*4+reg
    unsigned b1[8], b2[8];
#pragma unroll
    for (int k = 0; k < 8; ++k) { b1[k] = 0xFFFFFFFFu; b2[k] = 0xFFFFFFFFu; }

    const char* gh = (const char*)wh + (size_t)q * GROUPS_PER_QUARTER * 16384;

    // prologue: stage group 0 into buf0 (4 async16/thread: 256*4*16 = 16 KB)
#pragma unroll
    for (int i = 0; i < 4; ++i) {
        int seg = w + i * 4;                       // wave-uniform, 0..15
        async_lds16(gh + seg * 1024 + L * 16, lds + seg * 1024);
    }
    __syncthreads();

    for (int ci = 0; ci < GROUPS_PER_QUARTER; ++ci) {
        const char* cur = lds + (ci & 1) * 16384;
        if (ci + 1 < GROUPS_PER_QUARTER) {
            const char* gn = gh + (ci + 1) * 16384;
            char* nxt = lds + ((ci + 1) & 1) * 16384;
#pragma unroll
            for (int i = 0; i < 4; ++i) {
                int seg = w + i * 4;
                async_lds16(gn + seg * 1024 + L * 16, nxt + seg * 1024);
            }
        }

        const int kbase = (q * GROUPS_PER_QUARTER + ci) * GROUP_C + chalf * 32;
        float c2v[2];
        c2v[0] = c2h[kbase + n16];
        c2v[1] = c2h[kbase + 16 + n16];

        floatx4 acc[2][2];
#pragma unroll
        for (int rt = 0; rt < 2; ++rt)
#pragma unroll
            for (int ct = 0; ct < 2; ++ct)
#pragma unroll
                for (int reg = 0; reg < 4; ++reg)
                    acc[rt][ct][reg] = c2v[ct] + x2q[rt][reg];

#pragma unroll
        for (int ks = 0; ks < 4; ++ks) {
            const half8* pb = (const half8*)cur + (ks * 4 + quad) * 64 + chalf * 32 + n16;
            half8 B0 = pb[0];
            half8 B1 = pb[16];
            acc[0][0] = __builtin_amdgcn_mfma_f32_16x16x32_f16(Ah[0][ks], B0, acc[0][0], 0, 0, 0);
            acc[1][0] = __builtin_amdgcn_mfma_f32_16x16x32_f16(Ah[1][ks], B0, acc[1][0], 0, 0, 0);
            acc[0][1] = __builtin_amdgcn_mfma_f32_16x16x32_f16(Ah[0][ks], B1, acc[0][1], 0, 0, 0);
            acc[1][1] = __builtin_amdgcn_mfma_f32_16x16x32_f16(Ah[1][ks], B1, acc[1][1], 0, 0, 0);
        }

        // key-packed best-2 insert: 6 uint ops per slot (2 scores)
        unsigned lc0 = (unsigned)(ci * 2);
        unsigned lc1 = (unsigned)(ci * 2 + 1);
#pragma unroll
        for (int rt = 0; rt < 2; ++rt)
#pragma unroll
            for (int reg = 0; reg < 4; ++reg) {
                unsigned k0 = (__float_as_uint(acc[rt][0][reg]) & 0xFFFFFFC0u) | lc0;
                unsigned k1 = (__float_as_uint(acc[rt][1][reg]) & 0xFFFFFFC0u) | lc1;
                unsigned kq = min(k0, k1);
                int k = rt * 4 + reg;
                b2[k] = min(b2[k], max(b1[k], kq));
                b1[k] = min(b1[k], kq);
            }

        __syncthreads();   // prefetch drained (had full compute phase) + cur free
    }

    int* candL = (int*)lds;       // [64 rows][8 candidates] — buffers dead now

    // decode keys -> (key, global idx), then merge sorted best-2 across 8 lanes
#pragma unroll
    for (int k = 0; k < 8; ++k) {
        unsigned v1 = b1[k], v2 = b2[k];
        int lc1i = (int)(v1 & 63u), lc2i = (int)(v2 & 63u);
        int p1 = (q * GROUPS_PER_QUARTER + (lc1i >> 1)) * GROUP_C + chalf * 32 + (lc1i & 1) * 16 + n16;
        int p2 = (q * GROUPS_PER_QUARTER + (lc2i >> 1)) * GROUP_C + chalf * 32 + (lc2i & 1) * 16 + n16;
#pragma unroll
        for (int m = 1; m < 8; m <<= 1) {
            unsigned o1 = (unsigned)__shfl_xor((int)v1, m, 64);
            unsigned o2 = (unsigned)__shfl_xor((int)v2, m, 64);
            int      q1 = __shfl_xor(p1, m, 64);
            int      q2 = __shfl_xor(p2, m, 64);
            bool firstMine = (v1 < o1) || (v1 == o1 && p1 < q1);
            unsigned nv1 = firstMine ? v1 : o1;  int np1 = firstMine ? p1 : q1;
            unsigned cb  = firstMine ? o1 : v1;  int cpi = firstMine ? q1 : p1;  // loser of firsts
            unsigned ob  = firstMine ? v2 : o2;  int obi = firstMine ? p2 : q2;  // winner's own 2nd
            bool secOwn = (ob < cb) || (ob == cb && obi < cpi);
            v1 = nv1; p1 = np1;
            v2 = secOwn ? ob : cb;  p2 = secOwn ? obi : cpi;
        }
        if ((n16 & 7) == 0) {
            int rloc = rq * 32 + (k >> 2) * 16 + quad * 4 + (k & 3);
            int g = chalf * 2 + (n16 >> 3);
            candL[rloc * 8 + g * 2 + 0] = p1;
            candL[rloc * 8 + g * 2 + 1] = p2;
        }
    }
    __syncthreads();

    // exact fp32 refine: 8 candidates/row, 2 per thread (64 rows x 4 threads)
    {
        int r = t >> 2, p = t & 3;
        int ixa = candL[r * 8 + p * 2 + 0];
        int ixb = candL[r * 8 + p * 2 + 1];
        const float4* xr4 = (const float4*)(x + (size_t)(gr0 + r) * D);
        const float4* ca4 = (const float4*)(centers + (size_t)ixa * D);
        const float4* cb4 = (const float4*)(centers + (size_t)ixb * D);
        float dota = 0.f, dotb = 0.f, x2s = 0.f, c2a = 0.f, c2b = 0.f;
#pragma unroll
        for (int d4 = 0; d4 < 32; ++d4) {
            float4 xv = xr4[d4], av = ca4[d4], bv = cb4[d4];
            dota = fmaf(xv.x, av.x, dota); dota = fmaf(xv.y, av.y, dota);
            dota = fmaf(xv.z, av.z, dota); dota = fmaf(xv.w, av.w, dota);
            dotb = fmaf(xv.x, bv.x, dotb); dotb = fmaf(xv.y, bv.y, dotb);
            dotb = fmaf(xv.z, bv.z, dotb); dotb = fmaf(xv.w, bv.w, dotb);
            x2s = fmaf(xv.x, xv.x, x2s); x2s = fmaf(xv.y, xv.y, x2s);
            x2s = fmaf(xv.z, xv.z, x2s); x2s = fmaf(xv.w, xv.w, x2s);
            c2a = fmaf(av.x, av.x, c2a); c2a = fmaf(av.y, av.y, c2a);
            c2a = fmaf(av.z, av.z, c2a); c2a = fmaf(av.w, av.w, c2a);
            c2b = fmaf(bv.x, bv.x, c2b); c2b = fmaf(bv.y, bv.y, c2b);
            c2b = fmaf(bv.z, bv.z, c2b); c2b = fmaf(bv.w, bv.w, c2b);
        }
        float sqa = x2s + c2a - 2.f * dota;
        float sqb = x2s + c2b - 2.f * dotb;
        bool aw = (sqa < sqb) || (sqa == sqb && ixa < ixb);
        float sq = aw ? sqa : sqb;
        int   ix = aw ? ixa : ixb;
#pragma unroll
        for (int m = 1; m < 4; m <<= 1) {
            float osq = __shfl_xor(sq, m, 64);
            int   oix = __shfl_xor(ix, m, 64);
            if (osq < sq || (osq == sq && oix < ix)) { sq = osq; ix = oix; }
        }
        if (p == 0) {
            ws_sq[(size_t)q * BATCH + gr0 + r] = sq;
            ws_ix[(size_t)q * BATCH + gr0 + r] = ix;
        }
    }
}

// ---- final merge + outputs: one thread per (row, d4), 32 threads/row ----
__global__ __launch_bounds__(256) void final_kernel(
    const float* __restrict__ x, const float* __restrict__ centers,
    const float* __restrict__ ws_sq, const int* __restrict__ ws_ix,
    float* __restrict__ out) {
    int g = blockIdx.x * 256 + threadIdx.x;   // 0 .. BATCH*32-1
    int row = g >> 5, d4 = g & 31;

    // quarters have ascending disjoint index ranges: strict < keeps lowest idx on ties
    float sq = ws_sq[row];
    int   ix = ws_ix[row];
#pragma unroll
    for (int h = 1; h < QUARTERS; ++h) {
        float s2 = ws_sq[(size_t)h * BATCH + row];
        int   i2 = ws_ix[(size_t)h * BATCH + row];
        if (s2 < sq) { sq = s2; ix = i2; }
    }

    float* out_clu = out + (size_t)BATCH * D;
    float* out_md  = out_clu + BATCH;
    float* out_cls = out_md + BATCH;
    if (d4 == 0) {
        out_md[row]  = sqrtf(fmaxf(sq, 0.f));
        out_clu[row] = (float)(ix & (KC - 1));
        out_cls[row] = (float)(ix >> 6);
    }

    float4 cv = ((const float4*)centers)[(size_t)ix * 32 + d4];
    float4 xv = ((const float4*)x)[(size_t)row * 32 + d4];
    float4 o;
    o.x = xv.x + (cv.x - xv.x);
    o.y = xv.y + (cv.y - xv.y);
    o.z = xv.z + (cv.z - xv.z);
    o.w = xv.w + (cv.w - xv.w);
    ((float4*)out)[(size_t)row * 32 + d4] = o;
}

extern "C" void kernel_launch(void* const* d_in, const int* in_sizes, int n_in,
                              void* d_out, int out_size, void* d_ws, size_t ws_size,
                              hipStream_t stream) {
    const float* x       = (const float*)d_in[0];
    const float* centers = (const float*)d_in[1];
    // d_in[2] = labels (int64) — unused by the forward computation
    float* out = (float*)d_out;

    _Float16* wh    = (_Float16*)d_ws;                  // K*D halves, group-major
    float*    c2h   = (float*)(wh + (size_t)K * D);     // +0.5*||c||^2, K floats
    float*    ws_sq = c2h + K;                          // 4*BATCH floats
    int*      ws_ix = (int*)(ws_sq + QUARTERS * BATCH); // 4*BATCH ints

    pack_kernel<<<(K * 16) / 256, 256, 0, stream>>>(centers, wh, c2h);
    dim3 grid(BATCH / ROWS_PER_BLOCK, QUARTERS);
    dist_kernel<<<grid, 256, 0, stream>>>(x, centers, wh, c2h, ws_sq, ws_ix);
    final_kernel<<<(BATCH * 32) / 256, 256, 0, stream>>>(x, centers, ws_sq, ws_ix, out);
}